// Round 7
// baseline (250.984 us; speedup 1.0000x reference)
//
#include <hip/hip_runtime.h>
#include <hip/hip_bf16.h>

typedef __bf16 bf16x8 __attribute__((ext_vector_type(8)));
typedef float  float4v __attribute__((ext_vector_type(4)));
typedef unsigned short u16;
typedef u16 u16x8 __attribute__((ext_vector_type(8)));

#define NB 32
#define NT 2048
#define ND 512
#define NU 512
#define BK 64        // K per phase; 8 phases

__device__ __forceinline__ u16 f2bf(float f) {
    union { float f; unsigned u; } v; v.f = f;
    unsigned u = v.u;
    return (u16)((u + 0x7fffu + ((u >> 16) & 1u)) >> 16);  // RNE
}

// 8 fp32 -> 8 bf16 via packed converts
__device__ __forceinline__ u16x8 cvt8(float4v a, float4v b) {
    union { __hip_bfloat162 h[4]; u16x8 v; } u;
    u.h[0] = __float22bfloat162_rn(make_float2(a[0], a[1]));
    u.h[1] = __float22bfloat162_rn(make_float2(a[2], a[3]));
    u.h[2] = __float22bfloat162_rn(make_float2(b[0], b[1]));
    u.h[3] = __float22bfloat162_rn(make_float2(b[2], b[3]));
    return u.v;
}

__device__ __forceinline__ float fast_tanh(float x) {
    float e = __expf(-2.f * x);
    return 2.f / (1.f + e) - 1.f;
}

// ---- setup: W1->bf16 W1^T, projh, zero ctx_raw/Ssum ------------------------
__global__ void k_setup(const float* __restrict__ W1, u16* __restrict__ w1t,
                        const float* __restrict__ hidden, const float* __restrict__ W2,
                        const float* __restrict__ b2, float* __restrict__ projh,
                        float* __restrict__ ctx_raw, float* __restrict__ Ssum) {
    __shared__ u16 tile[32][33];
    __shared__ float h[ND];
    __shared__ float part[4][64];
    // zero accumulators: ctx_raw (16384 floats) across 512 blocks, Ssum (32)
    if (threadIdx.x < 32) ctx_raw[blockIdx.x * 32 + threadIdx.x] = 0.f;
    if (blockIdx.x == 0 && threadIdx.x >= 32 && threadIdx.x < 64)
        Ssum[threadIdx.x - 32] = 0.f;

    if (blockIdx.x < 256) {
        int bd = (blockIdx.x & 15) * 32;
        int bu = (blockIdx.x >> 4) * 32;
        int tx = threadIdx.x & 31, ty = threadIdx.x >> 5;
        #pragma unroll
        for (int i = 0; i < 4; ++i)
            tile[ty + i * 8][tx] = f2bf(W1[(bd + ty + i * 8) * NU + bu + tx]);
        __syncthreads();
        #pragma unroll
        for (int i = 0; i < 4; ++i)
            w1t[(bu + ty + i * 8) * ND + bd + tx] = tile[tx][ty + i * 8];
    } else {
        int blk = blockIdx.x - 256;
        int b  = blk >> 3;
        int uc = (blk & 7) * 64;
        int ui = threadIdx.x & 63;
        int du = threadIdx.x >> 6;
        for (int i = threadIdx.x; i < ND; i += 256) h[i] = hidden[b * ND + i];
        __syncthreads();
        int u = uc + ui;
        float acc = 0.f;
        int d0 = du * 128;
        #pragma unroll 8
        for (int d = 0; d < 128; ++d) acc += h[d0 + d] * W2[(d0 + d) * NU + u];
        part[du][ui] = acc;
        __syncthreads();
        if (threadIdx.x < 64)
            projh[b * NU + u] = part[0][ui] + part[1][ui] + part[2][ui] + part[3][ui] + b2[u];
    }
}

// ---- logits + context partial: block = 64 rows x FULL U=512, K=512 ---------
// v7: v4's verified GEMM body (79.6us) + flash-style epilogue, with the
// epilogue-2 context pass restructured for coalescing: 128 d-slots x float4
// (16B/lane) x 4 t-groups of 16 rows, LDS-combine in the free bT buffer,
// 4 atomics per d-slot. (v6's scalar 256B/wave loads cost +39us; this is
// the r5-k_ctxsm-proven access pattern.)
__global__ __launch_bounds__(512, 4)
void k_logits(const float* __restrict__ feat, const u16* __restrict__ w1t,
              const float* __restrict__ b1, const float* __restrict__ projh,
              const float* __restrict__ V, float* __restrict__ logits,
              float* __restrict__ ctx_raw, float* __restrict__ Ssum) {
    __shared__ __align__(16) u16 aT[64 * BK];    // 8 KB
    __shared__ __align__(16) u16 bT[512 * BK];   // 64 KB  (total 72 KB)

    const int row0 = blockIdx.x * 64;            // grid 1024
    const int b    = row0 >> 11;
    const int tid  = threadIdx.x;
    const int wave = tid >> 6, lane = tid & 63;
    const int quad = lane >> 4, col = lane & 15;

    float4v acc[4][4];
    #pragma unroll
    for (int mt = 0; mt < 4; ++mt)
        #pragma unroll
        for (int nt = 0; nt < 4; ++nt) acc[mt][nt] = (float4v)0.f;

    const int r_a = tid >> 3, c_a = tid & 7;
    const int wc_a = c_a ^ (r_a & 7);            // swizzled LDS chunk
    const float* agp = feat + (long)row0 * ND + r_a * ND + c_a * 8;

    float4v f0 = *(const float4v*)agp;
    float4v f1 = *(const float4v*)(agp + 4);

    for (int p = 0; p < 8; ++p) {
        const int k0 = p * BK;
        #pragma unroll
        for (int j = 0; j < 8; ++j) {
            int s  = j * 512 + tid;              // LDS dst slot = bT + s*16B
            int r  = s >> 3;
            int gc = (s & 7) ^ (r & 7);          // pre-swizzled global chunk
            const u16* gp = w1t + r * ND + k0 + gc * 8;
            u16* lp = &bT[(j * 512 + wave * 64) * 8];   // wave-uniform base
            __builtin_amdgcn_global_load_lds(
                (const __attribute__((address_space(1))) unsigned int*)gp,
                (__attribute__((address_space(3))) unsigned int*)lp, 16, 0, 0);
        }
        *(u16x8*)(&aT[r_a * BK + wc_a * 8]) = cvt8(f0, f1);
        __syncthreads();
        if (p < 7) {
            const float* gp = agp + (p + 1) * BK;
            f0 = *(const float4v*)gp;
            f1 = *(const float4v*)(gp + 4);
        }
        #pragma unroll
        for (int ks = 0; ks < 2; ++ks) {
            bf16x8 af[4], bf[4];
            #pragma unroll
            for (int mt = 0; mt < 4; ++mt) {
                int ra = mt * 16 + col;
                af[mt] = *(const bf16x8*)(&aT[ra * BK + (((ks * 4 + quad) ^ (ra & 7)) * 8)]);
            }
            #pragma unroll
            for (int nt = 0; nt < 4; ++nt) {
                int rb = wave * 64 + nt * 16 + col;
                bf[nt] = *(const bf16x8*)(&bT[rb * BK + (((ks * 4 + quad) ^ (rb & 7)) * 8)]);
            }
            #pragma unroll
            for (int nt = 0; nt < 4; ++nt)
                #pragma unroll
                for (int mt = 0; mt < 4; ++mt)
                    acc[mt][nt] = __builtin_amdgcn_mfma_f32_16x16x32_bf16(af[mt], bf[nt], acc[mt][nt], 0, 0, 0);
        }
        __syncthreads();
    }

    // ---- epilogue 1: per-row logit ----------------------------------------
    float b1v[4], phv[4], Vv[4];
    #pragma unroll
    for (int nt = 0; nt < 4; ++nt) {
        int u = wave * 64 + nt * 16 + col;
        b1v[nt] = b1[u];
        phv[nt] = projh[b * NU + u];
        Vv[nt]  = V[u];
    }
    float* fscr = (float*)aT;                  // LDS reuse: partial[8][64] + pw[64]
    float (*partial)[64] = (float(*)[64])fscr;
    float* pw = fscr + 512;
    #pragma unroll
    for (int mt = 0; mt < 4; ++mt) {
        #pragma unroll
        for (int rg = 0; rg < 4; ++rg) {
            float s = 0.f;
            #pragma unroll
            for (int nt = 0; nt < 4; ++nt) {
                float pv = acc[mt][nt][rg] + b1v[nt] + phv[nt];
                s += fast_tanh(pv) * Vv[nt];
            }
            s += __shfl_xor(s, 1);
            s += __shfl_xor(s, 2);
            s += __shfl_xor(s, 4);
            s += __shfl_xor(s, 8);
            if (col == 0) partial[wave][mt * 16 + quad * 4 + rg] = s;
        }
    }
    __syncthreads();
    if (tid < 64) {
        float v = 0.f;
        #pragma unroll
        for (int w = 0; w < 8; ++w) v += partial[w][tid];
        logits[row0 + tid] = v;
        float pe = __expf(v);                  // bounded: |v| <~ 20
        pw[tid] = pe;
        #pragma unroll
        for (int o = 1; o < 64; o <<= 1) pe += __shfl_xor(pe, o);
        if (tid == 0) atomicAdd(&Ssum[b], pe);
    }
    __syncthreads();

    // ---- epilogue 2: context partial, coalesced ---------------------------
    // 128 d-slots (float4, 16B/lane) x 4 t-groups of 16 rows; LDS-combine in
    // bT (free post-GEMM); 4 atomics per d-slot.
    {
        const int di = tid & 127, tg = tid >> 7;
        const float* fp = feat + (long)(row0 + tg * 16) * ND + di * 4;
        float4v c = (float4v)0.f;
        #pragma unroll
        for (int t = 0; t < 16; ++t)
            c += pw[tg * 16 + t] * *(const float4v*)(fp + (long)t * ND);
        float4v* cpart = (float4v*)bT;
        if (tg) cpart[(tg - 1) * 128 + di] = c;
        __syncthreads();
        if (!tg) {
            c += cpart[di] + cpart[128 + di] + cpart[256 + di];
            float* cp = &ctx_raw[b * ND + di * 4];
            atomicAdd(cp + 0, c[0]);
            atomicAdd(cp + 1, c[1]);
            atomicAdd(cp + 2, c[2]);
            atomicAdd(cp + 3, c[3]);
        }
    }
}

// ---- final: normalize ctx, produce attn ------------------------------------
__global__ void k_final(const float* __restrict__ logits, const float* __restrict__ ctx_raw,
                        const float* __restrict__ Ssum, float* __restrict__ ctx,
                        float* __restrict__ attn) {
    const int b = blockIdx.x, tid = threadIdx.x;   // 32 x 512
    const float invS = 1.f / Ssum[b];
    ctx[b * ND + tid] = ctx_raw[b * ND + tid] * invS;
    #pragma unroll
    for (int i = 0; i < 4; ++i) {
        int t = tid + i * 512;
        attn[b * NT + t] = __expf(logits[b * NT + t]) * invS;
    }
}

extern "C" void kernel_launch(void* const* d_in, const int* in_sizes, int n_in,
                              void* d_out, int out_size, void* d_ws, size_t ws_size,
                              hipStream_t stream) {
    const float* feat   = (const float*)d_in[0];
    const float* hidden = (const float*)d_in[1];
    const float* W1     = (const float*)d_in[2];
    const float* b1     = (const float*)d_in[3];
    const float* W2     = (const float*)d_in[4];
    const float* b2     = (const float*)d_in[5];
    const float* V      = (const float*)d_in[6];
    // d_in[7] = bv: unused — softmax(x + bv) == softmax(x)

    float* out_ctx  = (float*)d_out;            // [32,512]
    float* out_attn = (float*)d_out + NB * ND;  // [32,2048,1]

    u16*   w1t     = (u16*)d_ws;                                         // 512 KB
    float* projh   = (float*)((char*)d_ws + 512 * 1024);                 // 64 KB
    float* logits  = (float*)((char*)d_ws + 576 * 1024);                 // 256 KB
    float* ctx_raw = (float*)((char*)d_ws + 832 * 1024);                 // 64 KB
    float* Ssum    = (float*)((char*)d_ws + 896 * 1024);                 // 128 B

    k_setup <<<512, 256, 0, stream>>>(W1, w1t, hidden, W2, b2, projh, ctx_raw, Ssum);
    k_logits<<<1024, 512, 0, stream>>>(feat, w1t, b1, projh, V, logits, ctx_raw, Ssum);
    k_final <<<NB, 512, 0, stream>>>(logits, ctx_raw, Ssum, out_ctx, out_attn);
}